// Round 23
// baseline (101.993 us; speedup 1.0000x reference)
//
#include <hip/hip_runtime.h>
#include <stdint.h>

// Problem constants (SelfAttention: B=8, C=512, C8=64, W=2048)
#define B_  8
#define C_  512
#define CO_ 64
#define W_  2048
#define R_  640   // stacked projection rows: 64 q + 64 k + 512 v
#define LOG2E 1.4426950408889634f

typedef float f32x2 __attribute__((ext_vector_type(2)));
typedef float f32x4 __attribute__((ext_vector_type(4)));
typedef float f32x16 __attribute__((ext_vector_type(16)));
typedef __bf16 bf16x8 __attribute__((ext_vector_type(8)));
typedef __bf16 bf16x2 __attribute__((ext_vector_type(2)));
typedef unsigned u32x2 __attribute__((ext_vector_type(2)));
typedef unsigned u32x4 __attribute__((ext_vector_type(4)));
typedef unsigned short u16;
typedef u16 u16x8 __attribute__((ext_vector_type(8)));
typedef u16 u16x4 __attribute__((ext_vector_type(4)));
typedef u16 u16x2 __attribute__((ext_vector_type(2)));

static __device__ __forceinline__ float exp2g(float f){
  return __builtin_amdgcn_exp2f(f);    // v_exp_f32 (2^x)
}
static __device__ __forceinline__ u16 f2b(float f){
  union { float f; unsigned u; } v; v.f = f;
  unsigned r = v.u + 0x7FFFu + ((v.u >> 16) & 1u);  // RNE
  return (u16)(r >> 16);
}
static __device__ __forceinline__ bf16x8 ldb(const u16* p){
  return __builtin_bit_cast(bf16x8, *(const u16x8*)p);
}
static __device__ __forceinline__ f32x4 mfma16(bf16x8 a, bf16x8 b, f32x4 c){
  return __builtin_amdgcn_mfma_f32_16x16x32_bf16(a, b, c, 0, 0, 0);
}
static __device__ __forceinline__ f32x16 mfma32(bf16x8 a, bf16x8 b, f32x16 c){
  return __builtin_amdgcn_mfma_f32_32x32x16_bf16(a, b, c, 0, 0, 0);
}
// v_permlane32_swap_b32: vdst lanes[32:63] <-> vsrc lanes[0:31]
static __device__ __forceinline__ void pl32swap(unsigned &a, unsigned &b){
  asm("v_permlane32_swap_b32 %0, %1" : "+v"(a), "+v"(b));
}
static __device__ __forceinline__ float red_sum32(float v){
  unsigned a = __builtin_bit_cast(unsigned, v), b = a;
  pl32swap(a, b);
  return __builtin_bit_cast(float, a) + __builtin_bit_cast(float, b);
}
static __device__ __forceinline__ unsigned pkbf(float lo, float hi){
  bf16x2 t; t[0] = (__bf16)lo; t[1] = (__bf16)hi;
  return __builtin_bit_cast(unsigned, t);
}
// raw barrier: drain ONLY LDS (lgkmcnt); VMEM prefetches stay in flight
static __device__ __forceinline__ void barrier_lds_only(){
  asm volatile("s_waitcnt lgkmcnt(0)" ::: "memory");
  __builtin_amdgcn_s_barrier();
}

// ---------------- K0: stack + cast weights/bias to bf16 (A fragment-major) -
// A-frag (16m x 32c) for mfma16 stored contiguous: af[mt16][kk][lane][8],
// lane = (c-chunk g)*16 + (m-row r). Q rows pre-scaled by log2(e) for exp2.
__global__ __launch_bounds__(256) void prep_w(
    const float* __restrict__ Wq, const float* __restrict__ bq,
    const float* __restrict__ Wk, const float* __restrict__ bk,
    const float* __restrict__ Wv, const float* __restrict__ bv,
    u16* __restrict__ af, float* __restrict__ ball){
  int e = blockIdx.x * 256 + threadIdx.x;
  if (e < R_ * C_){
    int r = e >> 9, c = e & (C_ - 1);
    float w;
    if (r < 64)       w = Wq[r * C_ + c] * LOG2E;
    else if (r < 128) w = Wk[(r - 64) * C_ + c];
    else              w = Wv[(r - 128) * C_ + c];
    int mt16 = r >> 4, mr = r & 15;
    int kk = c >> 5, g = (c >> 3) & 3, e8 = c & 7;
    af[(((size_t)mt16 * 16 + kk) * 64 + g * 16 + mr) * 8 + e8] = f2b(w);
  }
  if (e < R_){
    float bb;
    if (e < 64)       bb = bq[e] * LOG2E;
    else if (e < 128) bb = bk[e - 64];
    else              bb = bv[e - 128];
    ball[e] = bb;
  }
}

// ---------------- K2: fused transpose + projection GEMM (v6 = v4 + PADB514) -
// Grid (32 w-tiles, 8 b) x 1024 thr (16 waves = 4 groups of 4). Pipelined
// B-panel staging (dbuf t, 4-deep f32x2 ring, 1 barrier/cc); 8-deep A ring.
// PADB=514: row stride 257 dwords == 1 mod 32 -> m-loop ds_read_b128 ~2-way
// (was 8-way at 520). Group ws owns m-tiles {ws, ws+4, ws+8}.
//  Q/K out: f[(w/32)][(o/16)][lane=((o>>3)&1)*32 + (w&31)][e=o&7]
//  V   out: f[(c/32)][(j/16)][lane=((j>>3)&1)*32 + (c&31)][e=j&7]
#define PADB 514
__global__ __launch_bounds__(1024, 4) void gemm_fused(
    const u16* __restrict__ af, const float* __restrict__ ball,
    const float* __restrict__ x, u16* __restrict__ qf,
    u16* __restrict__ kf, u16* __restrict__ vf){
  __shared__ u16 bt[64][PADB];        // B-panel: [w][c], 65.8 KB
  __shared__ float t[2][32][65];      // f32 transpose staging dbuf, 16.6 KB
  __shared__ u16 vt[4][64][68];       // V repack buffer per ws-group, 34.8 KB
  int b = blockIdx.y;
  int w0 = blockIdx.x * 64;
  int tid = threadIdx.x, lane = tid & 63, wid = tid >> 6;
  int ws = wid >> 2, wm = (wid >> 1) & 1, wn = wid & 1;
  int g = lane >> 4, r = lane & 15;
  const float* xb = x + (size_t)b * C_ * W_;

  // ---- A prefetch ring: first m-tile (mt=ws), kk 0..7, issued up front ----
  const u16* apc0 = af + ((size_t)((ws * 4 + wm * 2) * 16) * 64 + lane) * 8;
  const u16* apc1 = apc0 + 8192;
  bf16x8 a[8][2];
  #pragma unroll
  for (int k = 0; k < 8; k++){
    a[k][0] = ldb(apc0 + k * 512);
    a[k][1] = ldb(apc1 + k * 512);
  }

  // ---- pipelined B-panel staging: 16 cc-phases, 1 barrier each ----
  {
    int rrow = tid >> 5, wseg = (tid & 31) * 2;      // global read mapping
    int tw = tid >> 4, cseg = (tid & 15) * 2;        // transpose mapping
    auto ldx = [&](int cc) -> f32x2 {
      return *(const f32x2*)&xb[(size_t)(cc * 32 + rrow) * W_ + w0 + wseg];
    };
    auto st_t = [&](int buf, f32x2 v){
      t[buf][rrow][wseg + 0] = v[0]; t[buf][rrow][wseg + 1] = v[1];
    };
    auto rd_bt = [&](int cc, int buf){
      u16x2 pk;
      pk[0] = f2b(t[buf][cseg + 0][tw]);
      pk[1] = f2b(t[buf][cseg + 1][tw]);
      *(u16x2*)&bt[tw][cc * 32 + cseg] = pk;
    };
    f32x2 v[4];
    #pragma unroll
    for (int k = 0; k < 4; k++) v[k] = ldx(k);
    st_t(0, v[0]);
    v[0] = ldx(4);
    barrier_lds_only();
    #pragma unroll
    for (int p = 0; p < 16; p++){
      rd_bt(p, p & 1);
      if (p < 15) st_t((p + 1) & 1, v[(p + 1) & 3]);
      if (p + 5 < 16) v[(p + 1) & 3] = ldx(p + 5);
      barrier_lds_only();
    }
  }

  // ---- m-tile loop: group ws does m-tiles ws, ws+4, ws+8 (3 iterations) ----
  for (int it = 0; it < 3; ++it){
    int mt = ws + it * 4;
    bool active = mt < 10;
    int mtn = (mt + 4 < 10) ? mt + 4 : ws;  // next tile (dummy when done)
    const u16* apn0 = af + ((size_t)((mtn * 4 + wm * 2) * 16) * 64 + lane) * 8;
    const u16* apn1 = apn0 + 8192;
    f32x4 acc[2][2] = {};
    if (active){
      #pragma unroll
      for (int kk = 0; kk < 16; kk++){
        bf16x8 b0 = ldb(&bt[wn * 32 +  0 + r][kk * 32 + g * 8]);
        bf16x8 b1 = ldb(&bt[wn * 32 + 16 + r][kk * 32 + g * 8]);
        acc[0][0] = mfma16(a[kk & 7][0], b0, acc[0][0]);
        acc[0][1] = mfma16(a[kk & 7][0], b1, acc[0][1]);
        acc[1][0] = mfma16(a[kk & 7][1], b0, acc[1][0]);
        acc[1][1] = mfma16(a[kk & 7][1], b1, acc[1][1]);
        if (kk < 8){
          a[kk][0] = ldb(apc0 + (kk + 8) * 512);
          a[kk][1] = ldb(apc1 + (kk + 8) * 512);
        } else {
          a[kk - 8][0] = ldb(apn0 + (kk - 8) * 512);
          a[kk - 8][1] = ldb(apn1 + (kk - 8) * 512);
        }
      }
      apc0 = apn0; apc1 = apn1;
    }

    if (active && mt < 2){
      // Q/K epilogue: direct fragment-major u16x4 stores (no LDS)
      u16* base = (mt == 0 ? qf : kf) + (size_t)b * W_ * CO_;
      #pragma unroll
      for (int i = 0; i < 2; i++){
        #pragma unroll
        for (int n = 0; n < 2; n++){
          int rbase = mt * 64 + wm * 32 + i * 16 + g * 4;
          int wcol  = w0 + wn * 32 + n * 16 + r;
          int o0 = (rbase & 63);
          int oc = o0 >> 4, h2 = (o0 >> 3) & 1, e0 = o0 & 7;
          u16x4 pk;
          #pragma unroll
          for (int tt = 0; tt < 4; tt++) pk[tt] = f2b(acc[i][n][tt] + ball[rbase + tt]);
          *(u16x4*)&base[((size_t)((wcol >> 5) * 4 + oc) * 64 + h2 * 32 + (wcol & 31)) * 8 + e0] = pk;
        }
      }
    } else if (active){
      // V epilogue part 1: repack into LDS vt[ws]
      #pragma unroll
      for (int i = 0; i < 2; i++){
        #pragma unroll
        for (int n = 0; n < 2; n++){
          int cT = wm * 32 + i * 16 + g * 4;
          int wT = wn * 32 + n * 16 + r;
          int rb = mt * 64 + cT;
          #pragma unroll
          for (int tt = 0; tt < 4; tt++)
            vt[ws][cT + tt][wT] = f2b(acc[i][n][tt] + ball[rb + tt]);
        }
      }
    }
    barrier_lds_only();
    if (active && mt >= 2){
      // V epilogue part 2: coalesced u16x8 stores
      int jt = wid & 3;            // wave-in-group x 2 cg = 8 frags
      int h2 = lane >> 5, li = lane & 31;
      u16* vfb_ = vf + (size_t)b * C_ * W_;
      #pragma unroll
      for (int cg = 0; cg < 2; cg++){
        u16x4 lo = *(const u16x4*)&vt[ws][cg * 32 + li][jt * 16 + h2 * 8];
        u16x4 hi4 = *(const u16x4*)&vt[ws][cg * 32 + li][jt * 16 + h2 * 8 + 4];
        u16x8 val = {lo[0], lo[1], lo[2], lo[3], hi4[0], hi4[1], hi4[2], hi4[3]};
        size_t off = ((size_t)(((mt - 2) * 2 + cg) * (W_ / 16) + (w0 >> 4) + jt) * 64 + lane) * 8;
        *(u16x8*)&vfb_[off] = val;
      }
    }
    barrier_lds_only();
  }
}

// ---------------- K3: P-shared flash attention v16 (8 j-tiles/macro) ------
// 256 blocks x 512 thr. 8 macros x 8 j-tiles, 9 barriers. Wave (jw=wv&3,
// iw=wv>>2) sphases j-tiles 8m+jw (half 0) and 8m+4+jw (half 1) for i-tile
// iw. P LDS pb[buf][it][half][32][132] keeps the conflict-free 132-stride.
// Raw barriers (T3/T4), rolling V prefetch over 8 steps, dual K streams, T5.
__global__ __launch_bounds__(512, 2) void attn16(
    const u16* __restrict__ qf, const u16* __restrict__ kf,
    const u16* __restrict__ vf, const float* __restrict__ x,
    const float* __restrict__ gamma, float* __restrict__ out){
  __shared__ u16 pb[2][2][2][32][132]; // [buf][i-tile][half][i][j(swz)]
  __shared__ float lredf[2][4][32];    // per (i-tile, j-slot) row sums
  int tid = threadIdx.x, lane = tid & 63, wv = tid >> 6;
  int jw = wv & 3, iw = wv >> 2;
  int bid = blockIdx.x;
  int b = bid & 7;
  int i0 = (bid >> 3) * 64;
  int cbase = wv * 64;
  int li = lane & 31, hi = lane >> 5;
  int swz = (li & 7) << 3;             // XOR key, bits 3..5 of j
  const u16* qfb = qf + (size_t)b * W_ * CO_;
  const u16* kfb = kf + (size_t)b * W_ * CO_;
  const u16* vfb = vf + (size_t)b * C_ * W_;

  // Q B-frags for sphase i-tile iw: qf[(i0/32)+iw][oc][lane][8]
  bf16x8 fq[4];
  {
    const u16* qp = &qfb[(size_t)((i0 >> 5) + iw) * 4 * 512 + lane * 8];
    #pragma unroll
    for (int oc = 0; oc < 4; oc++) fq[oc] = ldb(qp + oc * 512);
  }

  // streaming bases: K streams for j-slots jw and jw+4; V for 2 c-tiles
  const u16* kp = &kfb[(size_t)jw * 2048 + lane * 8];   // += 16384 per macro
  const u16* vpt0 = &vfb[(size_t)(cbase >> 5) * (W_ / 16) * 512 + lane * 8];
  const u16* vpt1 = vpt0 + (size_t)(W_ / 16) * 512;     // += 8192 per macro

  f32x16 acc00 = {}, acc01 = {}, acc10 = {}, acc11 = {};  // [ct][it]
  f32x4 lacc = {};

  // softmax + P-write for one j-tile into (buffer bsel, half h)
  auto sphase = [&](bf16x8 (&fk)[4], int bsel, int h){
    f32x16 S = {};
    S = mfma32(fk[0], fq[0], S);
    S = mfma32(fk[1], fq[1], S);
    S = mfma32(fk[2], fq[2], S);
    S = mfma32(fk[3], fq[3], S);
    float p[16];
    #pragma unroll
    for (int t = 0; t < 16; t++) p[t] = exp2g(S[t]);
    #pragma unroll
    for (int t = 0; t < 4; t++)
      lacc[t] += ((p[t] + p[4 + t]) + (p[8 + t] + p[12 + t]));
    #pragma unroll
    for (int B = 0; B < 4; B++){
      unsigned lo = pkbf(p[4 * B + 0], p[4 * B + 1]);
      unsigned h2 = pkbf(p[4 * B + 2], p[4 * B + 3]);
      int j0 = (jw * 32 + 8 * B + 4 * hi) ^ swz;
      u32x2 wpair = {lo, h2};
      *(u32x2*)&pb[bsel][iw][h][li][j0] = wpair;
    }
  };
  // read P B-frag for (i-tile it, half h, j-tile jj, K-chunk kj)
  auto pfrag = [&](int bsel, int it, int h, int jj, int kj) -> bf16x8 {
    int j0 = (jj * 32 + kj * 16 + 8 * hi) ^ swz;
    u16x4 a = *(const u16x4*)&pb[bsel][it][h][li][j0];
    u16x4 c = *(const u16x4*)&pb[bsel][it][h][li][j0 + 4];
    u16x8 w = {a[0], a[1], a[2], a[3], c[0], c[1], c[2], c[3]};
    return __builtin_bit_cast(bf16x8, w);
  };
  // load the 4 V frags (2 c-tiles x 2 K-chunks) for one jj at u16 offset
  auto loadV = [&](bf16x8 (&fv)[4], int off){
    fv[0] = ldb(vpt0 + off); fv[1] = ldb(vpt0 + off + 512);
    fv[2] = ldb(vpt1 + off); fv[3] = ldb(vpt1 + off + 512);
  };
  // PV for one (half, jj): V frags x P frags of both i-tiles (V reused 2x)
  auto PV = [&](bf16x8 (&fv)[4], int bsel, int h, int jj){
    bf16x8 p00 = pfrag(bsel, 0, h, jj, 0), p01 = pfrag(bsel, 0, h, jj, 1);
    bf16x8 p10 = pfrag(bsel, 1, h, jj, 0), p11 = pfrag(bsel, 1, h, jj, 1);
    __builtin_amdgcn_s_setprio(1);
    acc00 = mfma32(fv[0], p00, acc00); acc00 = mfma32(fv[1], p01, acc00);
    acc10 = mfma32(fv[2], p00, acc10); acc10 = mfma32(fv[3], p01, acc10);
    acc01 = mfma32(fv[0], p10, acc01); acc01 = mfma32(fv[1], p11, acc01);
    acc11 = mfma32(fv[2], p10, acc11); acc11 = mfma32(fv[3], p11, acc11);
    __builtin_amdgcn_s_setprio(0);
  };

  bf16x8 fvX[4], fvY[4];
  // prologue: S(macro 0, both halves) -> buf 0; V jj0 in flight
  {
    bf16x8 fk[4];
    #pragma unroll
    for (int oc = 0; oc < 4; oc++) fk[oc] = ldb(kp + oc * 512);
    sphase(fk, 0, 0);
    #pragma unroll
    for (int oc = 0; oc < 4; oc++) fk[oc] = ldb(kp + 8192 + oc * 512);
    sphase(fk, 0, 1);
  }
  loadV(fvX, 0);
  barrier_lds_only();

  int cur = 0;
  for (int m = 0; m < 8; ++m){
    // K loads for macro m+1 (both j-slots) — consumed in sphase at macro end
    bf16x8 fkN[4], fkN2[4];
    if (m < 7){
      const u16* kpn = kp + 16384;
      #pragma unroll
      for (int oc = 0; oc < 4; oc++) fkN[oc]  = ldb(kpn + oc * 512);
      #pragma unroll
      for (int oc = 0; oc < 4; oc++) fkN2[oc] = ldb(kpn + 8192 + oc * 512);
    }
    // 8 jj-steps: rolling X/Y prefetch, PV(half, jj)
    loadV(fvY, 1024); PV(fvX, cur, 0, 0);
    loadV(fvX, 2048); PV(fvY, cur, 0, 1);
    loadV(fvY, 3072); PV(fvX, cur, 0, 2);
    loadV(fvX, 4096); PV(fvY, cur, 0, 3);
    loadV(fvY, 5120); PV(fvX, cur, 1, 0);
    loadV(fvX, 6144); PV(fvY, cur, 1, 1);
    loadV(fvY, 7168); PV(fvX, cur, 1, 2);
    if (m < 7) loadV(fvX, 8192);
    PV(fvY, cur, 1, 3);
    // S + P-write for macro m+1 into the other buffer (both halves)
    if (m < 7){
      sphase(fkN,  cur ^ 1, 0);
      sphase(fkN2, cur ^ 1, 1);
    }
    kp += 16384; vpt0 += 8192; vpt1 += 8192;
    // raw barrier: LDS drained, VMEM prefetches stay in flight (T3/T4)
    barrier_lds_only();
    cur ^= 1;
  }

  // l reduction: wave (jw,iw) has partial row sums for i-tile iw
  float l = (lacc[0] + lacc[1]) + (lacc[2] + lacc[3]);
  l = red_sum32(l);
  if (hi == 0) lredf[iw][jw][li] = l;
  __syncthreads();
  float lf0 = (lredf[0][0][li] + lredf[0][1][li]) + (lredf[0][2][li] + lredf[0][3][li]);
  float lf1 = (lredf[1][0][li] + lredf[1][1][li]) + (lredf[1][2][li] + lredf[1][3][li]);

  float gm = gamma[0];
  float iv0 = 1.f / lf0, iv1 = 1.f / lf1;
  const float* xb = x + (size_t)b * C_ * W_;
  float* ob = out + (size_t)b * C_ * W_;
  auto epi = [&](f32x16 &acc, int ct, int it, float iv){
    int icol = i0 + it * 32 + li;
    #pragma unroll
    for (int t = 0; t < 16; t++){
      int crow = (t & 3) + 8 * (t >> 2) + 4 * hi;
      int c = cbase + ct * 32 + crow;
      ob[(size_t)c * W_ + icol] = gm * (acc[t] * iv) + xb[(size_t)c * W_ + icol];
    }
  };
  epi(acc00, 0, 0, iv0); epi(acc10, 1, 0, iv0);
  epi(acc01, 0, 1, iv1); epi(acc11, 1, 1, iv1);
}

extern "C" void kernel_launch(void* const* d_in, const int* in_sizes, int n_in,
                              void* d_out, int out_size, void* d_ws, size_t ws_size,
                              hipStream_t stream) {
  const float* x     = (const float*)d_in[0];
  const float* Wq    = (const float*)d_in[1];
  const float* bq    = (const float*)d_in[2];
  const float* Wk    = (const float*)d_in[3];
  const float* bk    = (const float*)d_in[4];
  const float* Wv    = (const float*)d_in[5];
  const float* bv    = (const float*)d_in[6];
  const float* gamma = (const float*)d_in[7];
  float* out = (float*)d_out;
  char* ws = (char*)d_ws;
  // workspace layout (~22 MB used)
  u16*   af   = (u16*)  (ws + 0);         // 640*512*2        = 655360
  float* ball = (float*)(ws + 655360);    // 640*4            = 2560
  u16*   qf   = (u16*)  (ws + 17435136);  // 8*2048*64*2      = 2097152
  u16*   kf   = (u16*)  (ws + 19532288);  // 8*2048*64*2      = 2097152
  u16*   vf   = (u16*)  (ws + 21629440);  // 8*512*2048*2     = 16777216

  prep_w<<<dim3(1280), dim3(256), 0, stream>>>(Wq, bq, Wk, bk, Wv, bv, af, ball);
  gemm_fused<<<dim3(32, 8), dim3(1024), 0, stream>>>(af, ball, x, qf, kf, vf);
  attn16<<<dim3(256), dim3(512), 0, stream>>>(qf, kf, vf, x, gamma, out);
}

// Round 24
// 80.585 us; speedup vs baseline: 1.2657x; 1.2657x over previous
//
#include <hip/hip_runtime.h>
#include <stdint.h>

// Problem constants (SelfAttention: B=8, C=512, C8=64, W=2048)
#define B_  8
#define C_  512
#define CO_ 64
#define W_  2048
#define R_  640   // stacked projection rows: 64 q + 64 k + 512 v
#define LOG2E 1.4426950408889634f

typedef float f32x2 __attribute__((ext_vector_type(2)));
typedef float f32x4 __attribute__((ext_vector_type(4)));
typedef float f32x16 __attribute__((ext_vector_type(16)));
typedef __bf16 bf16x8 __attribute__((ext_vector_type(8)));
typedef __bf16 bf16x2 __attribute__((ext_vector_type(2)));
typedef unsigned u32x2 __attribute__((ext_vector_type(2)));
typedef unsigned u32x4 __attribute__((ext_vector_type(4)));
typedef unsigned short u16;
typedef u16 u16x8 __attribute__((ext_vector_type(8)));
typedef u16 u16x4 __attribute__((ext_vector_type(4)));
typedef u16 u16x2 __attribute__((ext_vector_type(2)));

static __device__ __forceinline__ float exp2g(float f){
  return __builtin_amdgcn_exp2f(f);    // v_exp_f32 (2^x)
}
static __device__ __forceinline__ u16 f2b(float f){
  union { float f; unsigned u; } v; v.f = f;
  unsigned r = v.u + 0x7FFFu + ((v.u >> 16) & 1u);  // RNE
  return (u16)(r >> 16);
}
static __device__ __forceinline__ bf16x8 ldb(const u16* p){
  return __builtin_bit_cast(bf16x8, *(const u16x8*)p);
}
static __device__ __forceinline__ f32x4 mfma16(bf16x8 a, bf16x8 b, f32x4 c){
  return __builtin_amdgcn_mfma_f32_16x16x32_bf16(a, b, c, 0, 0, 0);
}
static __device__ __forceinline__ f32x16 mfma32(bf16x8 a, bf16x8 b, f32x16 c){
  return __builtin_amdgcn_mfma_f32_32x32x16_bf16(a, b, c, 0, 0, 0);
}
// v_permlane32_swap_b32: vdst lanes[32:63] <-> vsrc lanes[0:31]
static __device__ __forceinline__ void pl32swap(unsigned &a, unsigned &b){
  asm("v_permlane32_swap_b32 %0, %1" : "+v"(a), "+v"(b));
}
static __device__ __forceinline__ float red_sum32(float v){
  unsigned a = __builtin_bit_cast(unsigned, v), b = a;
  pl32swap(a, b);
  return __builtin_bit_cast(float, a) + __builtin_bit_cast(float, b);
}
static __device__ __forceinline__ unsigned pkbf(float lo, float hi){
  bf16x2 t; t[0] = (__bf16)lo; t[1] = (__bf16)hi;
  return __builtin_bit_cast(unsigned, t);
}
// raw barrier: drain ONLY LDS (lgkmcnt); VMEM prefetches stay in flight
static __device__ __forceinline__ void barrier_lds_only(){
  asm volatile("s_waitcnt lgkmcnt(0)" ::: "memory");
  __builtin_amdgcn_s_barrier();
}

// ---------------- K0: stack + cast weights/bias to bf16 (A fragment-major) -
// A-frag (16m x 32c) for mfma16 stored contiguous: af[mt16][kk][lane][8],
// lane = (c-chunk g)*16 + (m-row r). Q rows pre-scaled by log2(e) for exp2.
__global__ __launch_bounds__(256) void prep_w(
    const float* __restrict__ Wq, const float* __restrict__ bq,
    const float* __restrict__ Wk, const float* __restrict__ bk,
    const float* __restrict__ Wv, const float* __restrict__ bv,
    u16* __restrict__ af, float* __restrict__ ball){
  int e = blockIdx.x * 256 + threadIdx.x;
  if (e < R_ * C_){
    int r = e >> 9, c = e & (C_ - 1);
    float w;
    if (r < 64)       w = Wq[r * C_ + c] * LOG2E;
    else if (r < 128) w = Wk[(r - 64) * C_ + c];
    else              w = Wv[(r - 128) * C_ + c];
    int mt16 = r >> 4, mr = r & 15;
    int kk = c >> 5, g = (c >> 3) & 3, e8 = c & 7;
    af[(((size_t)mt16 * 16 + kk) * 64 + g * 16 + mr) * 8 + e8] = f2b(w);
  }
  if (e < R_){
    float bb;
    if (e < 64)       bb = bq[e] * LOG2E;
    else if (e < 128) bb = bk[e - 64];
    else              bb = bv[e - 128];
    ball[e] = bb;
  }
}

// ---------------- K2: fused transpose + projection GEMM (v4, 1024 thr) -----
// Grid (32 w-tiles, 8 b) x 1024 thr (16 waves = 4 groups of 4). Same traffic
// and LDS as v2 but 4 waves/SIMD for latency hiding. Group ws owns m-tiles
// {ws, ws+4, ws+8} over 3 aligned iterations (2 barriers each). Pipelined
// B-panel staging (dbuf t, 4-deep f32x2 ring, 1 barrier/cc); 8-deep A ring.
//  Q/K out: f[(w/32)][(o/16)][lane=((o>>3)&1)*32 + (w&31)][e=o&7]
//  V   out: f[(c/32)][(j/16)][lane=((j>>3)&1)*32 + (c&31)][e=j&7]
#define PADB 520
__global__ __launch_bounds__(1024, 4) void gemm_fused(
    const u16* __restrict__ af, const float* __restrict__ ball,
    const float* __restrict__ x, u16* __restrict__ qf,
    u16* __restrict__ kf, u16* __restrict__ vf){
  __shared__ u16 bt[64][PADB];        // B-panel: [w][c], 66.5 KB
  __shared__ float t[2][32][65];      // f32 transpose staging dbuf, 16.6 KB
  __shared__ u16 vt[4][64][68];       // V repack buffer per ws-group, 34.8 KB
  int b = blockIdx.y;
  int w0 = blockIdx.x * 64;
  int tid = threadIdx.x, lane = tid & 63, wid = tid >> 6;
  int ws = wid >> 2, wm = (wid >> 1) & 1, wn = wid & 1;
  int g = lane >> 4, r = lane & 15;
  const float* xb = x + (size_t)b * C_ * W_;

  // ---- A prefetch ring: first m-tile (mt=ws), kk 0..7, issued up front ----
  const u16* apc0 = af + ((size_t)((ws * 4 + wm * 2) * 16) * 64 + lane) * 8;
  const u16* apc1 = apc0 + 8192;
  bf16x8 a[8][2];
  #pragma unroll
  for (int k = 0; k < 8; k++){
    a[k][0] = ldb(apc0 + k * 512);
    a[k][1] = ldb(apc1 + k * 512);
  }

  // ---- pipelined B-panel staging: 16 cc-phases, 1 barrier each ----
  {
    int rrow = tid >> 5, wseg = (tid & 31) * 2;      // global read mapping
    int tw = tid >> 4, cseg = (tid & 15) * 2;        // transpose mapping
    auto ldx = [&](int cc) -> f32x2 {
      return *(const f32x2*)&xb[(size_t)(cc * 32 + rrow) * W_ + w0 + wseg];
    };
    auto st_t = [&](int buf, f32x2 v){
      t[buf][rrow][wseg + 0] = v[0]; t[buf][rrow][wseg + 1] = v[1];
    };
    auto rd_bt = [&](int cc, int buf){
      u16x2 pk;
      pk[0] = f2b(t[buf][cseg + 0][tw]);
      pk[1] = f2b(t[buf][cseg + 1][tw]);
      *(u16x2*)&bt[tw][cc * 32 + cseg] = pk;
    };
    f32x2 v[4];
    #pragma unroll
    for (int k = 0; k < 4; k++) v[k] = ldx(k);
    st_t(0, v[0]);
    v[0] = ldx(4);
    barrier_lds_only();
    #pragma unroll
    for (int p = 0; p < 16; p++){
      rd_bt(p, p & 1);
      if (p < 15) st_t((p + 1) & 1, v[(p + 1) & 3]);
      if (p + 5 < 16) v[(p + 1) & 3] = ldx(p + 5);
      barrier_lds_only();
    }
  }

  // ---- m-tile loop: group ws does m-tiles ws, ws+4, ws+8 (3 iterations) ----
  for (int it = 0; it < 3; ++it){
    int mt = ws + it * 4;
    bool active = mt < 10;
    int mtn = (mt + 4 < 10) ? mt + 4 : ws;  // next tile (dummy when done)
    const u16* apn0 = af + ((size_t)((mtn * 4 + wm * 2) * 16) * 64 + lane) * 8;
    const u16* apn1 = apn0 + 8192;
    f32x4 acc[2][2] = {};
    if (active){
      #pragma unroll
      for (int kk = 0; kk < 16; kk++){
        bf16x8 b0 = ldb(&bt[wn * 32 +  0 + r][kk * 32 + g * 8]);
        bf16x8 b1 = ldb(&bt[wn * 32 + 16 + r][kk * 32 + g * 8]);
        acc[0][0] = mfma16(a[kk & 7][0], b0, acc[0][0]);
        acc[0][1] = mfma16(a[kk & 7][0], b1, acc[0][1]);
        acc[1][0] = mfma16(a[kk & 7][1], b0, acc[1][0]);
        acc[1][1] = mfma16(a[kk & 7][1], b1, acc[1][1]);
        if (kk < 8){
          a[kk][0] = ldb(apc0 + (kk + 8) * 512);
          a[kk][1] = ldb(apc1 + (kk + 8) * 512);
        } else {
          a[kk - 8][0] = ldb(apn0 + (kk - 8) * 512);
          a[kk - 8][1] = ldb(apn1 + (kk - 8) * 512);
        }
      }
      apc0 = apn0; apc1 = apn1;
    }

    if (active && mt < 2){
      // Q/K epilogue: direct fragment-major u16x4 stores (no LDS)
      u16* base = (mt == 0 ? qf : kf) + (size_t)b * W_ * CO_;
      #pragma unroll
      for (int i = 0; i < 2; i++){
        #pragma unroll
        for (int n = 0; n < 2; n++){
          int rbase = mt * 64 + wm * 32 + i * 16 + g * 4;
          int wcol  = w0 + wn * 32 + n * 16 + r;
          int o0 = (rbase & 63);
          int oc = o0 >> 4, h2 = (o0 >> 3) & 1, e0 = o0 & 7;
          u16x4 pk;
          #pragma unroll
          for (int tt = 0; tt < 4; tt++) pk[tt] = f2b(acc[i][n][tt] + ball[rbase + tt]);
          *(u16x4*)&base[((size_t)((wcol >> 5) * 4 + oc) * 64 + h2 * 32 + (wcol & 31)) * 8 + e0] = pk;
        }
      }
    } else if (active){
      // V epilogue part 1: repack into LDS vt[ws]
      #pragma unroll
      for (int i = 0; i < 2; i++){
        #pragma unroll
        for (int n = 0; n < 2; n++){
          int cT = wm * 32 + i * 16 + g * 4;
          int wT = wn * 32 + n * 16 + r;
          int rb = mt * 64 + cT;
          #pragma unroll
          for (int tt = 0; tt < 4; tt++)
            vt[ws][cT + tt][wT] = f2b(acc[i][n][tt] + ball[rb + tt]);
        }
      }
    }
    barrier_lds_only();
    if (active && mt >= 2){
      // V epilogue part 2: coalesced u16x8 stores
      int jt = wid & 3;            // wave-in-group x 2 cg = 8 frags
      int h2 = lane >> 5, li = lane & 31;
      u16* vfb_ = vf + (size_t)b * C_ * W_;
      #pragma unroll
      for (int cg = 0; cg < 2; cg++){
        u16x4 lo = *(const u16x4*)&vt[ws][cg * 32 + li][jt * 16 + h2 * 8];
        u16x4 hi4 = *(const u16x4*)&vt[ws][cg * 32 + li][jt * 16 + h2 * 8 + 4];
        u16x8 val = {lo[0], lo[1], lo[2], lo[3], hi4[0], hi4[1], hi4[2], hi4[3]};
        size_t off = ((size_t)(((mt - 2) * 2 + cg) * (W_ / 16) + (w0 >> 4) + jt) * 64 + lane) * 8;
        *(u16x8*)&vfb_[off] = val;
      }
    }
    barrier_lds_only();
  }
}

// ---------------- K3: P-shared flash attention v16 (8 j-tiles/macro) ------
// 256 blocks x 512 thr. 8 macros x 8 j-tiles, 9 barriers. Wave (jw=wv&3,
// iw=wv>>2) sphases j-tiles 8m+jw (half 0) and 8m+4+jw (half 1) for i-tile
// iw. P LDS pb[buf][it][half][32][132] keeps the conflict-free 132-stride.
// Raw barriers (T3/T4), rolling V prefetch over 8 steps, dual K streams, T5.
__global__ __launch_bounds__(512, 2) void attn16(
    const u16* __restrict__ qf, const u16* __restrict__ kf,
    const u16* __restrict__ vf, const float* __restrict__ x,
    const float* __restrict__ gamma, float* __restrict__ out){
  __shared__ u16 pb[2][2][2][32][132]; // [buf][i-tile][half][i][j(swz)]
  __shared__ float lredf[2][4][32];    // per (i-tile, j-slot) row sums
  int tid = threadIdx.x, lane = tid & 63, wv = tid >> 6;
  int jw = wv & 3, iw = wv >> 2;
  int bid = blockIdx.x;
  int b = bid & 7;
  int i0 = (bid >> 3) * 64;
  int cbase = wv * 64;
  int li = lane & 31, hi = lane >> 5;
  int swz = (li & 7) << 3;             // XOR key, bits 3..5 of j
  const u16* qfb = qf + (size_t)b * W_ * CO_;
  const u16* kfb = kf + (size_t)b * W_ * CO_;
  const u16* vfb = vf + (size_t)b * C_ * W_;

  // Q B-frags for sphase i-tile iw: qf[(i0/32)+iw][oc][lane][8]
  bf16x8 fq[4];
  {
    const u16* qp = &qfb[(size_t)((i0 >> 5) + iw) * 4 * 512 + lane * 8];
    #pragma unroll
    for (int oc = 0; oc < 4; oc++) fq[oc] = ldb(qp + oc * 512);
  }

  // streaming bases: K streams for j-slots jw and jw+4; V for 2 c-tiles
  const u16* kp = &kfb[(size_t)jw * 2048 + lane * 8];   // += 16384 per macro
  const u16* vpt0 = &vfb[(size_t)(cbase >> 5) * (W_ / 16) * 512 + lane * 8];
  const u16* vpt1 = vpt0 + (size_t)(W_ / 16) * 512;     // += 8192 per macro

  f32x16 acc00 = {}, acc01 = {}, acc10 = {}, acc11 = {};  // [ct][it]
  f32x4 lacc = {};

  // softmax + P-write for one j-tile into (buffer bsel, half h)
  auto sphase = [&](bf16x8 (&fk)[4], int bsel, int h){
    f32x16 S = {};
    S = mfma32(fk[0], fq[0], S);
    S = mfma32(fk[1], fq[1], S);
    S = mfma32(fk[2], fq[2], S);
    S = mfma32(fk[3], fq[3], S);
    float p[16];
    #pragma unroll
    for (int t = 0; t < 16; t++) p[t] = exp2g(S[t]);
    #pragma unroll
    for (int t = 0; t < 4; t++)
      lacc[t] += ((p[t] + p[4 + t]) + (p[8 + t] + p[12 + t]));
    #pragma unroll
    for (int B = 0; B < 4; B++){
      unsigned lo = pkbf(p[4 * B + 0], p[4 * B + 1]);
      unsigned h2 = pkbf(p[4 * B + 2], p[4 * B + 3]);
      int j0 = (jw * 32 + 8 * B + 4 * hi) ^ swz;
      u32x2 wpair = {lo, h2};
      *(u32x2*)&pb[bsel][iw][h][li][j0] = wpair;
    }
  };
  // read P B-frag for (i-tile it, half h, j-tile jj, K-chunk kj)
  auto pfrag = [&](int bsel, int it, int h, int jj, int kj) -> bf16x8 {
    int j0 = (jj * 32 + kj * 16 + 8 * hi) ^ swz;
    u16x4 a = *(const u16x4*)&pb[bsel][it][h][li][j0];
    u16x4 c = *(const u16x4*)&pb[bsel][it][h][li][j0 + 4];
    u16x8 w = {a[0], a[1], a[2], a[3], c[0], c[1], c[2], c[3]};
    return __builtin_bit_cast(bf16x8, w);
  };
  // load the 4 V frags (2 c-tiles x 2 K-chunks) for one jj at u16 offset
  auto loadV = [&](bf16x8 (&fv)[4], int off){
    fv[0] = ldb(vpt0 + off); fv[1] = ldb(vpt0 + off + 512);
    fv[2] = ldb(vpt1 + off); fv[3] = ldb(vpt1 + off + 512);
  };
  // PV for one (half, jj): V frags x P frags of both i-tiles (V reused 2x)
  auto PV = [&](bf16x8 (&fv)[4], int bsel, int h, int jj){
    bf16x8 p00 = pfrag(bsel, 0, h, jj, 0), p01 = pfrag(bsel, 0, h, jj, 1);
    bf16x8 p10 = pfrag(bsel, 1, h, jj, 0), p11 = pfrag(bsel, 1, h, jj, 1);
    __builtin_amdgcn_s_setprio(1);
    acc00 = mfma32(fv[0], p00, acc00); acc00 = mfma32(fv[1], p01, acc00);
    acc10 = mfma32(fv[2], p00, acc10); acc10 = mfma32(fv[3], p01, acc10);
    acc01 = mfma32(fv[0], p10, acc01); acc01 = mfma32(fv[1], p11, acc01);
    acc11 = mfma32(fv[2], p10, acc11); acc11 = mfma32(fv[3], p11, acc11);
    __builtin_amdgcn_s_setprio(0);
  };

  bf16x8 fvX[4], fvY[4];
  // prologue: S(macro 0, both halves) -> buf 0; V jj0 in flight
  {
    bf16x8 fk[4];
    #pragma unroll
    for (int oc = 0; oc < 4; oc++) fk[oc] = ldb(kp + oc * 512);
    sphase(fk, 0, 0);
    #pragma unroll
    for (int oc = 0; oc < 4; oc++) fk[oc] = ldb(kp + 8192 + oc * 512);
    sphase(fk, 0, 1);
  }
  loadV(fvX, 0);
  barrier_lds_only();

  int cur = 0;
  for (int m = 0; m < 8; ++m){
    // K loads for macro m+1 (both j-slots) — consumed in sphase at macro end
    bf16x8 fkN[4], fkN2[4];
    if (m < 7){
      const u16* kpn = kp + 16384;
      #pragma unroll
      for (int oc = 0; oc < 4; oc++) fkN[oc]  = ldb(kpn + oc * 512);
      #pragma unroll
      for (int oc = 0; oc < 4; oc++) fkN2[oc] = ldb(kpn + 8192 + oc * 512);
    }
    // 8 jj-steps: rolling X/Y prefetch, PV(half, jj)
    loadV(fvY, 1024); PV(fvX, cur, 0, 0);
    loadV(fvX, 2048); PV(fvY, cur, 0, 1);
    loadV(fvY, 3072); PV(fvX, cur, 0, 2);
    loadV(fvX, 4096); PV(fvY, cur, 0, 3);
    loadV(fvY, 5120); PV(fvX, cur, 1, 0);
    loadV(fvX, 6144); PV(fvY, cur, 1, 1);
    loadV(fvY, 7168); PV(fvX, cur, 1, 2);
    if (m < 7) loadV(fvX, 8192);
    PV(fvY, cur, 1, 3);
    // S + P-write for macro m+1 into the other buffer (both halves)
    if (m < 7){
      sphase(fkN,  cur ^ 1, 0);
      sphase(fkN2, cur ^ 1, 1);
    }
    kp += 16384; vpt0 += 8192; vpt1 += 8192;
    // raw barrier: LDS drained, VMEM prefetches stay in flight (T3/T4)
    barrier_lds_only();
    cur ^= 1;
  }

  // l reduction: wave (jw,iw) has partial row sums for i-tile iw
  float l = (lacc[0] + lacc[1]) + (lacc[2] + lacc[3]);
  l = red_sum32(l);
  if (hi == 0) lredf[iw][jw][li] = l;
  __syncthreads();
  float lf0 = (lredf[0][0][li] + lredf[0][1][li]) + (lredf[0][2][li] + lredf[0][3][li]);
  float lf1 = (lredf[1][0][li] + lredf[1][1][li]) + (lredf[1][2][li] + lredf[1][3][li]);

  float gm = gamma[0];
  float iv0 = 1.f / lf0, iv1 = 1.f / lf1;
  const float* xb = x + (size_t)b * C_ * W_;
  float* ob = out + (size_t)b * C_ * W_;
  auto epi = [&](f32x16 &acc, int ct, int it, float iv){
    int icol = i0 + it * 32 + li;
    #pragma unroll
    for (int t = 0; t < 16; t++){
      int crow = (t & 3) + 8 * (t >> 2) + 4 * hi;
      int c = cbase + ct * 32 + crow;
      ob[(size_t)c * W_ + icol] = gm * (acc[t] * iv) + xb[(size_t)c * W_ + icol];
    }
  };
  epi(acc00, 0, 0, iv0); epi(acc10, 1, 0, iv0);
  epi(acc01, 0, 1, iv1); epi(acc11, 1, 1, iv1);
}

extern "C" void kernel_launch(void* const* d_in, const int* in_sizes, int n_in,
                              void* d_out, int out_size, void* d_ws, size_t ws_size,
                              hipStream_t stream) {
  const float* x     = (const float*)d_in[0];
  const float* Wq    = (const float*)d_in[1];
  const float* bq    = (const float*)d_in[2];
  const float* Wk    = (const float*)d_in[3];
  const float* bk    = (const float*)d_in[4];
  const float* Wv    = (const float*)d_in[5];
  const float* bv    = (const float*)d_in[6];
  const float* gamma = (const float*)d_in[7];
  float* out = (float*)d_out;
  char* ws = (char*)d_ws;
  // workspace layout (~22 MB used)
  u16*   af   = (u16*)  (ws + 0);         // 640*512*2        = 655360
  float* ball = (float*)(ws + 655360);    // 640*4            = 2560
  u16*   qf   = (u16*)  (ws + 17435136);  // 8*2048*64*2      = 2097152
  u16*   kf   = (u16*)  (ws + 19532288);  // 8*2048*64*2      = 2097152
  u16*   vf   = (u16*)  (ws + 21629440);  // 8*512*2048*2     = 16777216

  prep_w<<<dim3(1280), dim3(256), 0, stream>>>(Wq, bq, Wk, bk, Wv, bv, af, ball);
  gemm_fused<<<dim3(32, 8), dim3(1024), 0, stream>>>(af, ball, x, qf, kf, vf);
  attn16<<<dim3(256), dim3(512), 0, stream>>>(qf, kf, vf, x, gamma, out);
}